// Round 14
// baseline (128.262 us; speedup 1.0000x reference)
//
#include <hip/hip_runtime.h>
#include <hip/hip_bf16.h>

// Shapes: x(8,16,4,64,64) f32, W(256,16,5,5) f32, b(1,1,8,32) f32
// out(8,32,8,64,64) f32.
//
// Reference reshapes (verified passing through R13):
//   conv input  t2[n,a,h,w] = x[b0, fl&15, ci, fl>>10, (fl>>4)&63],
//     fl = a*4096 + h*64 + w, n = ci*8 + b0
//   votes flat (n,oc,y,x) reinterpreted by routing as (bv,civ,h,w,o,ao).
//   conv+routing fusion impossible (routing row needs ALL conv y's).
//
// LEDGER:
//  - Softmax max-subtract removal: FAILED R3+R5. Do not re-try (kept).
//  - Inline-asm permlane swap: FAILED (R7/R8). Builtins only (R9/R12-proven).
//  - Routing TLP x2 / ILP x2: null. 2-pos-per-wave (R12): -2us, kept. FROZEN.
//  - conv R6 2-stage pipeline best of the 1-y variants (R11 deeper aw
//    prefetch: worse). pack merge (R13): -2.8us, kept.
//  - Under test this round (conv only): y-PAIR blocks — tile row r feeds
//    tap ky=r of y0 AND ky=r-1 of y1 with the SAME bf register (weight plane
//    p vs p-5); LDS reads -42%. accA = exact R13 sequence (bit-identical);
//    accB planes 0..24 each once (ulp reassociation only).

typedef _Float16 half8 __attribute__((ext_vector_type(8)));
typedef _Float16 half4v __attribute__((ext_vector_type(4)));
typedef float floatx4 __attribute__((ext_vector_type(4)));
typedef unsigned uint2v __attribute__((ext_vector_type(2)));

#define EPSF 1e-7f

// ---------- cross-lane reductions (builtins ONLY; no inline asm) ----------
template <int CTRL>
__device__ __forceinline__ float dppmov(float x) {
  return __int_as_float(__builtin_amdgcn_update_dpp(
      0, __float_as_int(x), CTRL, 0xf, 0xf, false));
}
__device__ __forceinline__ float red_g_add(float x) {
  x += dppmov<0xB1>(x);   // ^1
  x += dppmov<0x4E>(x);   // ^2
  return x;
}
__device__ __forceinline__ float red_o2_add(float x) {
  x += dppmov<0x124>(x);  // row_ror:4
  x += dppmov<0x128>(x);  // row_ror:8
  uint2v r = __builtin_amdgcn_permlane16_swap(
      __float_as_uint(x), __float_as_uint(x), false, false);
  return __uint_as_float(r[0]) + __uint_as_float(r[1]);
}
__device__ __forceinline__ float red_o2_max(float x) {
  x = fmaxf(x, dppmov<0x124>(x));
  x = fmaxf(x, dppmov<0x128>(x));
  uint2v r = __builtin_amdgcn_permlane16_swap(
      __float_as_uint(x), __float_as_uint(x), false, false);
  return fmaxf(__uint_as_float(r[0]), __uint_as_float(r[1]));
}

// Merged pack: blocks 0..255 = transpose pack; 256..359 = W repack. (R13 text)
__global__ __launch_bounds__(1024) void k_pack_all(const float* __restrict__ x,
                                                   const float* __restrict__ W,
                                                   _Float16* __restrict__ th,
                                                   _Float16* __restrict__ Wp) {
  __shared__ float lin[32 * 306 + 18];
  const int bid = blockIdx.x;            // 360 blocks
  const int tid = threadIdx.x;           // 0..1023

  if (bid >= 256) {
    int id = (bid - 256) * 1024 + tid;   // 0..106495 = 26*4096
    int a  = id & 15;
    int oc = (id >> 4) & 255;
    int kk = id >> 12;
    Wp[id] = (kk < 25) ? (_Float16)W[oc * 400 + a * 25 + kk] : (_Float16)0.0f;
    return;
  }

  const int n   = bid >> 3;
  const int a0h = (bid >> 2) & 1;
  const int W0  = (bid & 3) * 16;
  const int ci = n >> 3, b0 = n & 7;
  const float* xb = x + b0 * 262144 + ci * 4096 + W0;

  for (int p = 0; p < 2; ++p) {
    int rr = p * 256 + (tid >> 2);
    int q  = (tid & 3) * 4;
    int a1 = rr >> 5, m = rr & 31;
    float4 v = *(const float4*)(xb + a1 * 16384 + (a0h * 32 + m) * 64 + q);
    float* d = lin + m * 306 + a1 * 18 + q;
    d[0] = v.x; d[1] = v.y; d[2] = v.z; d[3] = v.w;
  }
  __syncthreads();

  _Float16* tb = th + (size_t)n * 65536 + a0h * 32768 + W0 * 128;
  {
    int hh = tid >> 8;
    int w1 = (tid >> 4) & 15;
    int a1 = tid & 15;
    half8 v;
#pragma unroll
    for (int j = 0; j < 8; ++j)
      v[j] = (_Float16)lin[(j * 4 + hh) * 306 + a1 * 18 + w1];
    *(half8*)(tb + hh * 8192 + w1 * 128 + a1 * 8) = v;
  }
}

// Conv v8: y-pair blocks. 1024 blocks = 32 n x 32 ypairs; 6-row tile.
// accA (y0): planes via wbase+s*8192 (self-clamps to zero-plane 25 at
// s=12,t=1) — EXACT R13 sequence. accB (y1): plane 2s+t-5 (s=2..14; s==2,t==0
// -> zero plane 25); same bf register as accA's step.
__global__ __launch_bounds__(512, 4) void k_conv(const _Float16* __restrict__ th,
                                                 const _Float16* __restrict__ Wp,
                                                 _Float16* __restrict__ votes) {
  __shared__ _Float16 lds[16384];   // input tile 816 chunks (6528 h); epilogue 32KB
  const int orig = blockIdx.x;      // 1024
  const int lid  = (orig & 7) * 128 + (orig >> 3);   // bijective (1024 % 8 == 0)
  const int ypair = lid & 31;
  const int n     = lid >> 5;
  const int y0    = ypair * 2;
  const int tid = threadIdx.x;

  for (int c = tid; c < 816; c += 512) {
    int a0h = c / 408;
    int rem = c - a0h * 408;
    int r   = rem / 68;
    int col = rem - r * 68;
    int row = y0 + r - 2;
    half8 v = {};
    if (col >= 2 && col <= 65 && row >= 0 && row < 64)
      v = *(const half8*)(th + (size_t)(((n * 2 + a0h) * 64 + row) * 64 + (col - 2)) * 8);
    *(half8*)(lds + c * 8) = v;
  }
  __syncthreads();

  const int lane  = tid & 63;
  const int wv    = tid >> 6;
  const int col16 = lane & 15;
  const int quad  = lane >> 4;
  const int t     = quad >> 1;
  const int a0h   = quad & 1;
  const int m0    = wv * 32;

  floatx4 accA[2][4] = {}, accB[2][4] = {};

  const int wrest = (m0 + col16) * 16 + a0h * 8;
  const _Float16* wbase = Wp + t * 4096 + wrest;
  const _Float16* lbase = lds + (a0h * 408 + col16) * 8;

  half8 bfc[4], bfn[4];
  {
    // s=0: kkb = t -> r=0, kx=t -> off = t
    const _Float16* lb = lbase + (t ? 1 : 0) * 8;
#pragma unroll
    for (int xt = 0; xt < 4; ++xt)
      bfc[xt] = *(const half8*)(lb + xt * 128);
  }

#pragma unroll
  for (int s = 0; s < 15; ++s) {
    if (s < 14) {
      const int kn0 = 2 * (s + 1);
      const int kn1 = 2 * (s + 1) + 1;
      const int offn0 = (kn0 / 5) * 68 + (kn0 % 5);
      const int offn1 = (kn1 / 5) * 68 + (kn1 % 5);
      const _Float16* lb = lbase + (t ? offn1 : offn0) * 8;
#pragma unroll
      for (int xt = 0; xt < 4; ++xt)
        bfn[xt] = *(const half8*)(lb + xt * 128);
    }
    if (s <= 12) {                      // y0: planes {2s, 2s+1}; s=12,t=1 -> 25 (zeros)
      half8 awA[2];
#pragma unroll
      for (int oct = 0; oct < 2; ++oct)
        awA[oct] = *(const half8*)(wbase + (size_t)s * 8192 + oct * 256);
#pragma unroll
      for (int oct = 0; oct < 2; ++oct)
#pragma unroll
        for (int xt = 0; xt < 4; ++xt)
          accA[oct][xt] = __builtin_amdgcn_mfma_f32_16x16x32_f16(
              awA[oct], bfc[xt], accA[oct][xt], 0, 0, 0);
    }
    if (s >= 2) {                       // y1: plane 2s+t-5; s==2,t==0 -> 25 (zeros)
      const _Float16* wb = (s == 2)
          ? (Wp + (t ? 0 : 25 * 4096) + wrest)
          : (wbase + (size_t)(s - 2) * 8192 - 4096);
      half8 awB[2];
#pragma unroll
      for (int oct = 0; oct < 2; ++oct)
        awB[oct] = *(const half8*)(wb + oct * 256);
#pragma unroll
      for (int oct = 0; oct < 2; ++oct)
#pragma unroll
        for (int xt = 0; xt < 4; ++xt)
          accB[oct][xt] = __builtin_amdgcn_mfma_f32_16x16x32_f16(
              awB[oct], bfc[xt], accB[oct][xt], 0, 0, 0);
    }
    if (s < 14) {
#pragma unroll
      for (int xt = 0; xt < 4; ++xt) bfc[xt] = bfn[xt];
    }
  }

  // ---- epilogue: two passes (y0 then y1), R13's staged writeout each ----
#pragma unroll
  for (int pass = 0; pass < 2; ++pass) {
    const floatx4 (&acc)[2][4] = pass ? accB : accA;
    __syncthreads();
#pragma unroll
    for (int oct = 0; oct < 2; ++oct)
#pragma unroll
      for (int xt = 0; xt < 4; ++xt)
#pragma unroll
        for (int r = 0; r < 4; ++r) {
          int oc = m0 + oct * 16 + quad * 4 + r;
          int xx = xt * 16 + col16;
          int sw = (oc & 15) >> 1;
          lds[oc * 64 + (xx ^ (sw << 3))] = (_Float16)acc[oct][xt][r];
        }
    __syncthreads();
    _Float16* vb2 = votes + (size_t)n * 1048576 + (y0 + pass) * 64;
#pragma unroll
    for (int it = 0; it < 4; ++it) {
      int idx = it * 512 + tid;
      int oc  = idx >> 3;
      int x0  = (idx & 7) << 3;
      int sw  = (oc & 15) >> 1;
      half8 hv = *(const half8*)(lds + oc * 64 + (x0 ^ (sw << 3)));
      *(half8*)(vb2 + (size_t)oc * 4096 + x0) = hv;
    }
  }
}

// Routing v9: R12/R13's EXACT passing version (2 positions per wave).
__global__ __launch_bounds__(256) void k_routing9(
    const _Float16* __restrict__ votes, const float* __restrict__ bias,
    float* __restrict__ out) {
  __shared__ float so[256 * 9];         // 9 KB, stride 9 + col^g swizzle
  const int tid  = threadIdx.x;
  const int lane = tid & 63;
  const int wv   = tid >> 6;            // 0..3
  const int bid  = blockIdx.x;          // 4096
  const int bv = bid >> 9;
  const int h  = (bid >> 3) & 63;
  const int W0 = (bid & 7) * 8;

  const int half = lane >> 5;
  const int o    = (lane >> 2) & 7;
  const int g    = lane & 3;
  const int col  = wv * 2 + half;
  const int w    = W0 + col;

  float bb[8];
  {
    const float4 b0 = *(const float4*)(bias + o * 32 + g * 8);
    const float4 b1 = *(const float4*)(bias + o * 32 + g * 8 + 4);
    bb[0]=b0.x; bb[1]=b0.y; bb[2]=b0.z; bb[3]=b0.w;
    bb[4]=b1.x; bb[5]=b1.y; bb[6]=b1.z; bb[7]=b1.w;
  }

  const _Float16* vb = votes + (size_t)bv * 4194304 + h * 16384 + w * 256
                     + o * 32 + g * 8;
  float v[4][8];
#pragma unroll
  for (int i = 0; i < 4; ++i) {
    half8 hv = *(const half8*)(vb + (size_t)i * 1048576);
#pragma unroll
    for (int j = 0; j < 8; ++j) v[i][j] = (float)hv[j];
  }

  float logit[4], act[8], pr[8];

#pragma unroll
  for (int j = 0; j < 8; ++j)
    pr[j] = fmaf(0.125f, (v[0][j] + v[1][j]) + (v[2][j] + v[3][j]), bb[j]);
  {
    float sq = pr[0]*pr[0];
#pragma unroll
    for (int j = 1; j < 8; ++j) sq = fmaf(pr[j], pr[j], sq);
    sq = red_g_add(sq);
    float sc = sq * __builtin_amdgcn_rcpf(1.f + sq)
                  * __builtin_amdgcn_rsqf(sq + EPSF);
#pragma unroll
    for (int j = 0; j < 8; ++j) act[j] = pr[j] * sc;
  }
#pragma unroll
  for (int i = 0; i < 4; ++i) {
    float ag = v[i][0] * act[0];
#pragma unroll
    for (int j = 1; j < 8; ++j) ag = fmaf(v[i][j], act[j], ag);
    logit[i] = red_g_add(ag);
  }

#pragma unroll
  for (int r = 1; r < 3; ++r) {
    float route[4];
#pragma unroll
    for (int i = 0; i < 4; ++i) {
      float m = red_o2_max(logit[i]);
      float e = __expf(logit[i] - m);
      float s = red_o2_add(e);
      route[i] = e * __builtin_amdgcn_rcpf(s);
    }
#pragma unroll
    for (int j = 0; j < 8; ++j) pr[j] = bb[j];
#pragma unroll
    for (int i = 0; i < 4; ++i)
#pragma unroll
      for (int j = 0; j < 8; ++j)
        pr[j] = fmaf(route[i], v[i][j], pr[j]);
    float sq = pr[0]*pr[0];
#pragma unroll
    for (int j = 1; j < 8; ++j) sq = fmaf(pr[j], pr[j], sq);
    sq = red_g_add(sq);
    float sc = sq * __builtin_amdgcn_rcpf(1.f + sq)
                  * __builtin_amdgcn_rsqf(sq + EPSF);
#pragma unroll
    for (int j = 0; j < 8; ++j) act[j] = pr[j] * sc;
    if (r < 2) {
#pragma unroll
      for (int i = 0; i < 4; ++i) {
        float ag = v[i][0] * act[0];
#pragma unroll
        for (int j = 1; j < 8; ++j) ag = fmaf(v[i][j], act[j], ag);
        logit[i] += red_g_add(ag);
      }
    }
  }

#pragma unroll
  for (int j = 0; j < 8; ++j)
    so[(g * 64 + j * 8 + o) * 9 + (col ^ g)] = act[j];
  __syncthreads();

  float* ob = out + (size_t)bv * 1048576 + h * 64 + W0;
#pragma unroll
  for (int p = 0; p < 4; ++p) {
    int r  = p * 64 + (tid >> 2);
    int c2 = (tid & 3) * 2;
    float lo = so[r * 9 + (c2 ^ p)];
    float hi = so[r * 9 + ((c2 + 1) ^ p)];
    *(float2*)(ob + (size_t)r * 4096 + c2) = make_float2(lo, hi);
  }
}

extern "C" void kernel_launch(void* const* d_in, const int* in_sizes, int n_in,
                              void* d_out, int out_size, void* d_ws, size_t ws_size,
                              hipStream_t stream) {
  const float* x  = (const float*)d_in[0];
  const float* W  = (const float*)d_in[1];
  const float* b  = (const float*)d_in[2];
  float* out = (float*)d_out;

  _Float16* th    = (_Float16*)d_ws;            // 2,097,152 halves (4 MB)
  _Float16* Wp    = th + 2097152;               // 106,496 halves (208 KB)
  _Float16* votes = Wp + 106496;                // 33,554,432 halves (64 MB)

  k_pack_all<<<360, 1024, 0, stream>>>(x, W, th, Wp);
  k_conv<<<1024, 512, 0, stream>>>(th, Wp, votes);
  k_routing9<<<4096, 256, 0, stream>>>(votes, b, out);
}